// Round 3
// baseline (493.075 us; speedup 1.0000x reference)
//
#include <hip/hip_runtime.h>

#define Bx 8
#define Nx 256
#define Lx 48
#define Fx 96
#define KP 104     // padded K stride in bf16 units (208 B, 16B-aligned)

typedef __attribute__((ext_vector_type(8))) short bf16x8;
typedef __attribute__((ext_vector_type(4))) float f32x4;

__device__ __forceinline__ unsigned short f2bf(float f) {
    unsigned int u = __float_as_uint(f);
    u += 0x7fffu + ((u >> 16) & 1u);       // RNE
    return (unsigned short)(u >> 16);
}
__device__ __forceinline__ unsigned int pack2(float a, float b) {
    return (unsigned int)f2bf(a) | ((unsigned int)f2bf(b) << 16);
}

// ---------------------------------------------------------------------------
// K_sums: single pass over x producing rowsum, colsum, diag.
// Block = (b, is, jc): i in [is*32, +32), j in [jc*16, +16). 1024 blocks.
// Per i-iteration the block reads 16*48 = 768 contiguous floats.
// colsum: per-thread register accumulation (thread owns fixed (j,l) elements).
// rowsum: LDS atomic partials rs[ii][l], flushed via global atomicAdd.
// rowsum/colsum must be pre-zeroed.
// ---------------------------------------------------------------------------
__global__ __launch_bounds__(256) void k_sums(const float* __restrict__ x,
                                              float* __restrict__ rowsum,
                                              float* __restrict__ colsum,
                                              float* __restrict__ diagv) {
    const int blk = blockIdx.x;
    const int jc = blk & 15;
    const int is = (blk >> 4) & 7;
    const int b  = blk >> 7;
    const int t  = threadIdx.x;

    __shared__ float rs[32 * 48];          // 6 KB partial rowsums
    #pragma unroll
    for (int k = 0; k < 6; ++k) rs[t + k * 256] = 0.f;
    __syncthreads();

    // element decomposition for the three strided slots
    const int j0 = (t)       / 48, l0 = (t)       % 48;
    const int j1 = (t + 256) / 48, l1 = (t + 256) % 48;
    const int j2 = (t + 512) / 48, l2 = (t + 512) % 48;

    const size_t base = (size_t)b * Nx * Nx * Lx + (size_t)(is * 32) * Nx * Lx
                      + (size_t)(jc * 16) * Lx;
    float ca0 = 0.f, ca1 = 0.f, ca2 = 0.f;

    for (int ii = 0; ii < 32; ++ii) {
        const int ig = is * 32 + ii;
        const float* p = x + base + (size_t)ii * Nx * Lx;
        const float v0 = p[t];
        const float v1 = p[t + 256];
        const float v2 = p[t + 512];
        ca0 += v0; ca1 += v1; ca2 += v2;
        atomicAdd(&rs[ii * 48 + l0], v0);
        atomicAdd(&rs[ii * 48 + l1], v1);
        atomicAdd(&rs[ii * 48 + l2], v2);
        const int jb = jc * 16;
        if (jb + j0 == ig) diagv[(size_t)(b * Nx + ig) * Lx + l0] = v0;
        if (jb + j1 == ig) diagv[(size_t)(b * Nx + ig) * Lx + l1] = v1;
        if (jb + j2 == ig) diagv[(size_t)(b * Nx + ig) * Lx + l2] = v2;
    }

    // colsum: thread owns (j = jc*16 + jk, l) -> flat offset == t (+256,+512)
    float* cs = colsum + ((size_t)b * Nx + jc * 16) * Lx;
    atomicAdd(cs + t,       ca0);
    atomicAdd(cs + t + 256, ca1);
    atomicAdd(cs + t + 512, ca2);

    __syncthreads();
    // flush rowsum partials: 1536 values / 256 threads = 6 each
    #pragma unroll
    for (int k = 0; k < 6; ++k) {
        const int idx = t + k * 256;
        const int ii = idx / 48, l = idx % 48;
        atomicAdd(&rowsum[(size_t)(b * Nx + is * 32 + ii) * Lx + l], rs[idx]);
    }
}

// ---------------------------------------------------------------------------
// K1b: trace[b,l] = sum_i diag[b,i,l]; totsum[b,l] = sum_i rowsum[b,i,l]
// ---------------------------------------------------------------------------
__global__ __launch_bounds__(64) void k1b_trace(const float* __restrict__ rowsum,
                                                const float* __restrict__ diagv,
                                                float* __restrict__ trace,
                                                float* __restrict__ totsum) {
    const int b = blockIdx.x;
    const int l = threadIdx.x;
    if (l >= Lx) return;
    float tr = 0.f, ts = 0.f;
    for (int i = 0; i < Nx; ++i) {
        const size_t idx = (size_t)(b * Nx + i) * Lx + l;
        tr += diagv[idx];
        ts += rowsum[idx];
    }
    trace[b * Lx + l]  = tr;
    totsum[b * Lx + l] = ts;
}

// ---------------------------------------------------------------------------
// K2: per-(b,n) f-vectors (fp32 exact)
// ---------------------------------------------------------------------------
__global__ __launch_bounds__(128) void k2_vectors(const float* __restrict__ w,
                                                  const float* __restrict__ rowsum,
                                                  const float* __restrict__ colsum,
                                                  const float* __restrict__ diagv,
                                                  const float* __restrict__ trace,
                                                  const float* __restrict__ totsum,
                                                  float* __restrict__ add_i,
                                                  float* __restrict__ add_j,
                                                  float* __restrict__ add_d) {
    const int blk = blockIdx.x;           // b*N + n
    const int b = blk >> 8;
    const int f = threadIdx.x;
    if (f >= Fx) return;

    const float* dP  = diagv  + (size_t)blk * Lx;
    const float* rP  = rowsum + (size_t)blk * Lx;
    const float* cP  = colsum + (size_t)blk * Lx;
    const float* trP = trace  + b * Lx;
    const float* tsP = totsum + b * Lx;

    float ai = 0.f, aj = 0.f, ad = 0.f;
    #pragma unroll 4
    for (int l = 0; l < Lx; ++l) {
        const float d  = dP[l];
        const float r  = rP[l];
        const float c  = cP[l];
        const float tr = trP[l];
        const float ts = tsP[l];
        const float* wl = w + (size_t)l * Fx + f;
        ad = fmaf(d,  wl[0  * Lx * Fx], ad);
        ad = fmaf(r,  wl[1  * Lx * Fx], ad);
        ad = fmaf(c,  wl[2  * Lx * Fx], ad);
        ad = fmaf(tr, wl[3  * Lx * Fx], ad);
        ad = fmaf(ts, wl[4  * Lx * Fx], ad);
        aj = fmaf(d,  wl[5  * Lx * Fx], aj);
        aj = fmaf(r,  wl[6  * Lx * Fx], aj);
        aj = fmaf(c,  wl[7  * Lx * Fx], aj);
        ai = fmaf(d,  wl[8  * Lx * Fx], ai);
        ai = fmaf(r,  wl[9  * Lx * Fx], ai);
        ai = fmaf(c,  wl[10 * Lx * Fx], ai);
        ai = fmaf(tr, wl[13 * Lx * Fx], ai);
        ai = fmaf(ts, wl[14 * Lx * Fx], ai);
    }
    add_i[(size_t)blk * Fx + f] = ai;
    add_j[(size_t)blk * Fx + f] = aj;
    add_d[(size_t)blk * Fx + f] = ad;
}

// ---------------------------------------------------------------------------
// K_w: wt[f][kk] (bf16, stride KP): kk<48 -> w12[kk][f], kk<96 -> w11[kk-48][f]
// ---------------------------------------------------------------------------
__global__ __launch_bounds__(256) void k_w(const float* __restrict__ w,
                                           unsigned short* __restrict__ wt) {
    const int idx = blockIdx.x * 256 + threadIdx.x;
    if (idx >= Fx * KP) return;
    const int f = idx / KP, kk = idx % KP;
    float v = 0.f;
    if (kk < 48)      v = w[12 * Lx * Fx + kk * Fx + f];
    else if (kk < 96) v = w[11 * Lx * Fx + (kk - 48) * Fx + f];
    wt[idx] = f2bf(v);
}

// ---------------------------------------------------------------------------
// K3: symmetric-pair MFMA pass. Block = (b, tile-pair ti<=tj), 16x16 tiles.
// Reads x tiles T1=(I,J), T2=(J,I) once; computes out tiles (I,J) AND (J,I):
//   out(I+il, J+jl) = T1[il,jl].w12 + T2[jl,il].w11
//   out(J+jl, I+il) = T2[jl,il].w12 + T1[il,jl].w11
// LDS A-row m=(il*16+jl) = [T1[il,jl,0:48] | T2[jl,il,0:48]] (bf16, stride KP).
// pass0 reads k as-is; pass1 reads k XOR-swapped halves ((k+48)%96).
// B (wt) read directly from global (20 KB, L1-resident).
// ---------------------------------------------------------------------------
__global__ __launch_bounds__(256) void k3_mfma(const float* __restrict__ x,
                                               const unsigned short* __restrict__ wt,
                                               const float* __restrict__ add_i,
                                               const float* __restrict__ add_j,
                                               const float* __restrict__ add_d,
                                               float* __restrict__ out) {
    __shared__ unsigned short Abuf[256 * KP];   // 53248 B

    // decode tile pair (uniform)
    int p = blockIdx.x;
    int ti = 0;
    while (p >= 16 - ti) { p -= 16 - ti; ++ti; }
    const int tj = ti + p;
    const int b  = blockIdx.y;
    const int I = ti * 16, J = tj * 16;
    const int t = threadIdx.x;

    const float* xb = x + (size_t)b * Nx * Nx * Lx;

    // stage T1: rows (I+il), cols (J..J+16): 768 contiguous floats per il
    #pragma unroll
    for (int it = 0; it < 12; ++it) {
        const int flat = it * 256 + t;          // 0..3071 float4s
        const int il = flat / 192;
        const int q  = flat % 192;
        const int jl = q / 12, l4 = q % 12;
        const float4 v = *(const float4*)(xb + ((size_t)(I + il) * Nx + (J + jl)) * Lx + l4 * 4);
        unsigned int* dst = (unsigned int*)Abuf + (il * 16 + jl) * (KP / 2) + l4 * 2;
        dst[0] = pack2(v.x, v.y);
        dst[1] = pack2(v.z, v.w);
    }
    // stage T2: rows (J+jl), cols (I..I+16)
    #pragma unroll
    for (int it = 0; it < 12; ++it) {
        const int flat = it * 256 + t;
        const int jl = flat / 192;
        const int q  = flat % 192;
        const int il = q / 12, l4 = q % 12;
        const float4 v = *(const float4*)(xb + ((size_t)(J + jl) * Nx + (I + il)) * Lx + l4 * 4);
        unsigned int* dst = (unsigned int*)Abuf + (il * 16 + jl) * (KP / 2) + 24 + l4 * 2;
        dst[0] = pack2(v.x, v.y);
        dst[1] = pack2(v.z, v.w);
    }
    __syncthreads();

    const int wave = t >> 6, lane = t & 63;
    const int lm = lane & 15, quad = lane >> 4;

    #pragma unroll
    for (int pass = 0; pass < 2; ++pass) {
        #pragma unroll
        for (int nt = 0; nt < 6; ++nt) {
            bf16x8 bfr[3];
            #pragma unroll
            for (int ks = 0; ks < 3; ++ks)
                bfr[ks] = *(const bf16x8*)(wt + (nt * 16 + lm) * KP + ks * 32 + quad * 8);

            f32x4 acc[4];
            #pragma unroll
            for (int mi = 0; mi < 4; ++mi) {
                f32x4 c = {0.f, 0.f, 0.f, 0.f};
                const int row = (wave * 4 + mi) * 16 + lm;
                #pragma unroll
                for (int ks = 0; ks < 3; ++ks) {
                    int off = ks * 32 + quad * 8;
                    if (pass) off = (off >= 48) ? off - 48 : off + 48;
                    const bf16x8 afr = *(const bf16x8*)(Abuf + row * KP + off);
                    c = __builtin_amdgcn_mfma_f32_16x16x32_bf16(afr, bfr[ks], c, 0, 0, 0);
                }
                acc[mi] = c;
            }

            // epilogue for this nt
            const int f = nt * 16 + lm;
            #pragma unroll
            for (int mi = 0; mi < 4; ++mi) {
                const int mt = wave * 4 + mi;    // il
                #pragma unroll
                for (int reg = 0; reg < 4; ++reg) {
                    const int jl2 = quad * 4 + reg;
                    const int i = pass ? (J + jl2) : (I + mt);
                    const int j = pass ? (I + mt)  : (J + jl2);
                    float v = acc[mi][reg]
                            + add_i[(size_t)(b * Nx + i) * Fx + f]
                            + add_j[(size_t)(b * Nx + j) * Fx + f];
                    if (i == j) v += add_d[(size_t)(b * Nx + i) * Fx + f];
                    out[((size_t)(b * Nx + i) * Nx + j) * Fx + f] = v;
                }
            }
        }
    }
}

// ---------------------------------------------------------------------------
extern "C" void kernel_launch(void* const* d_in, const int* in_sizes, int n_in,
                              void* d_out, int out_size, void* d_ws, size_t ws_size,
                              hipStream_t stream) {
    const float* x = (const float*)d_in[0];
    const float* w = (const float*)d_in[1];
    float* out = (float*)d_out;

    float* ws      = (float*)d_ws;
    float* rowsum  = ws;                                  // B*N*L
    float* colsum  = rowsum + (size_t)Bx * Nx * Lx;       // adjacent (joint memset)
    float* diagv   = colsum + (size_t)Bx * Nx * Lx;
    float* trace   = diagv  + (size_t)Bx * Nx * Lx;       // B*L
    float* totsum  = trace  + (size_t)Bx * Lx;
    float* add_i   = totsum + (size_t)Bx * Lx;            // B*N*F
    float* add_j   = add_i  + (size_t)Bx * Nx * Fx;
    float* add_d   = add_j  + (size_t)Bx * Nx * Fx;
    unsigned short* wtbf = (unsigned short*)(add_d + (size_t)Bx * Nx * Fx);

    hipMemsetAsync(rowsum, 0, 2 * (size_t)Bx * Nx * Lx * sizeof(float), stream);
    k_w<<<(Fx * KP + 255) / 256, 256, 0, stream>>>(w, wtbf);
    k_sums<<<Bx * 8 * 16, 256, 0, stream>>>(x, rowsum, colsum, diagv);
    k1b_trace<<<Bx, 64, 0, stream>>>(rowsum, diagv, trace, totsum);
    k2_vectors<<<Bx * Nx, 128, 0, stream>>>(w, rowsum, colsum, diagv, trace, totsum,
                                            add_i, add_j, add_d);
    dim3 g3(136, Bx);
    k3_mfma<<<g3, 256, 0, stream>>>(x, wtbf, add_i, add_j, add_d, out);
}

// Round 4
// 390.285 us; speedup vs baseline: 1.2634x; 1.2634x over previous
//
#include <hip/hip_runtime.h>

#define Bx 8
#define Nx 256
#define Lx 48
#define Fx 96
#define KP 104     // padded K stride in bf16 units (208 B, 16B-aligned)

typedef __attribute__((ext_vector_type(8))) short bf16x8;
typedef __attribute__((ext_vector_type(4))) float f32x4;

__device__ __forceinline__ unsigned short f2bf(float f) {
    unsigned int u = __float_as_uint(f);
    u += 0x7fffu + ((u >> 16) & 1u);       // RNE
    return (unsigned short)(u >> 16);
}
__device__ __forceinline__ unsigned int pack2(float a, float b) {
    return (unsigned int)f2bf(a) | ((unsigned int)f2bf(b) << 16);
}

// ---------------------------------------------------------------------------
// K_row: rowsum[b,i,l] = sum_j x[b,i,j,l] (contiguous); diag[b,i,l] = x[b,i,i,l]
// ---------------------------------------------------------------------------
__global__ __launch_bounds__(192) void k_row(const float* __restrict__ x,
                                             float* __restrict__ rowsum,
                                             float* __restrict__ diagv) {
    const int blk = blockIdx.x;           // b*N + i
    const int t = threadIdx.x;
    const int l = t % Lx;
    const int g = t / Lx;
    __shared__ float red[192];
    const size_t base = (size_t)blk * Nx * Lx;
    float acc = 0.f;
    for (int j = g; j < Nx; j += 4)
        acc += x[base + (size_t)j * Lx + l];
    red[t] = acc;
    __syncthreads();
    if (g == 0)
        rowsum[(size_t)blk * Lx + l] = red[l] + red[48 + l] + red[96 + l] + red[144 + l];
    if (t < Lx)
        diagv[(size_t)blk * Lx + t] = x[base + (size_t)(blk & 255) * Lx + t];
}

// ---------------------------------------------------------------------------
// K_col: colsum[b,j,l] = sum_i x[b,i,j,l]. Coalesced: block owns a 16-j chunk
// (16*48 = 768 contiguous floats per i), accumulates 32 i's, atomicAdd out.
// Grid = B * 16 jc * 8 isplit = 1024.  colsum must be zeroed first.
// ---------------------------------------------------------------------------
__global__ __launch_bounds__(256) void k_col(const float* __restrict__ x,
                                             float* __restrict__ colsum) {
    const int blk = blockIdx.x;
    const int is = blk & 7;
    const int jc = (blk >> 3) & 15;
    const int b  = blk >> 7;
    const int t = threadIdx.x;
    const size_t cb = (size_t)b * Nx * Nx * Lx + (size_t)jc * 16 * Lx;
    float a0 = 0.f, a1 = 0.f, a2 = 0.f;
    for (int ii = 0; ii < 32; ++ii) {
        const int i = is * 32 + ii;
        const float* p = x + cb + (size_t)i * Nx * Lx;
        a0 += p[t];
        a1 += p[t + 256];
        a2 += p[t + 512];
    }
    float* c = colsum + ((size_t)b * Nx + jc * 16) * Lx;
    atomicAdd(c + t, a0);
    atomicAdd(c + t + 256, a1);
    atomicAdd(c + t + 512, a2);
}

// ---------------------------------------------------------------------------
// K1b: trace[b,l] = sum_i diag[b,i,l]; totsum[b,l] = sum_i rowsum[b,i,l]
// ---------------------------------------------------------------------------
__global__ __launch_bounds__(64) void k1b_trace(const float* __restrict__ rowsum,
                                                const float* __restrict__ diagv,
                                                float* __restrict__ trace,
                                                float* __restrict__ totsum) {
    const int b = blockIdx.x;
    const int l = threadIdx.x;
    if (l >= Lx) return;
    float tr = 0.f, ts = 0.f;
    for (int i = 0; i < Nx; ++i) {
        const size_t idx = (size_t)(b * Nx + i) * Lx + l;
        tr += diagv[idx];
        ts += rowsum[idx];
    }
    trace[b * Lx + l]  = tr;
    totsum[b * Lx + l] = ts;
}

// ---------------------------------------------------------------------------
// K2: per-(b,n) f-vectors (fp32 exact)
// ---------------------------------------------------------------------------
__global__ __launch_bounds__(128) void k2_vectors(const float* __restrict__ w,
                                                  const float* __restrict__ rowsum,
                                                  const float* __restrict__ colsum,
                                                  const float* __restrict__ diagv,
                                                  const float* __restrict__ trace,
                                                  const float* __restrict__ totsum,
                                                  float* __restrict__ add_i,
                                                  float* __restrict__ add_j,
                                                  float* __restrict__ add_d) {
    const int blk = blockIdx.x;           // b*N + n
    const int b = blk >> 8;
    const int f = threadIdx.x;
    if (f >= Fx) return;

    const float* dP  = diagv  + (size_t)blk * Lx;
    const float* rP  = rowsum + (size_t)blk * Lx;
    const float* cP  = colsum + (size_t)blk * Lx;
    const float* trP = trace  + b * Lx;
    const float* tsP = totsum + b * Lx;

    float ai = 0.f, aj = 0.f, ad = 0.f;
    #pragma unroll 4
    for (int l = 0; l < Lx; ++l) {
        const float d  = dP[l];
        const float r  = rP[l];
        const float c  = cP[l];
        const float tr = trP[l];
        const float ts = tsP[l];
        const float* wl = w + (size_t)l * Fx + f;
        ad = fmaf(d,  wl[0  * Lx * Fx], ad);
        ad = fmaf(r,  wl[1  * Lx * Fx], ad);
        ad = fmaf(c,  wl[2  * Lx * Fx], ad);
        ad = fmaf(tr, wl[3  * Lx * Fx], ad);
        ad = fmaf(ts, wl[4  * Lx * Fx], ad);
        aj = fmaf(d,  wl[5  * Lx * Fx], aj);
        aj = fmaf(r,  wl[6  * Lx * Fx], aj);
        aj = fmaf(c,  wl[7  * Lx * Fx], aj);
        ai = fmaf(d,  wl[8  * Lx * Fx], ai);
        ai = fmaf(r,  wl[9  * Lx * Fx], ai);
        ai = fmaf(c,  wl[10 * Lx * Fx], ai);
        ai = fmaf(tr, wl[13 * Lx * Fx], ai);
        ai = fmaf(ts, wl[14 * Lx * Fx], ai);
    }
    add_i[(size_t)blk * Fx + f] = ai;
    add_j[(size_t)blk * Fx + f] = aj;
    add_d[(size_t)blk * Fx + f] = ad;
}

// ---------------------------------------------------------------------------
// K_w: wt[f][kk] (bf16, stride KP): kk<48 -> w12[kk][f], kk<96 -> w11[kk-48][f]
// ---------------------------------------------------------------------------
__global__ __launch_bounds__(256) void k_w(const float* __restrict__ w,
                                           unsigned short* __restrict__ wt) {
    const int idx = blockIdx.x * 256 + threadIdx.x;
    if (idx >= Fx * KP) return;
    const int f = idx / KP, kk = idx % KP;
    float v = 0.f;
    if (kk < 48)      v = w[12 * Lx * Fx + kk * Fx + f];
    else if (kk < 96) v = w[11 * Lx * Fx + (kk - 48) * Fx + f];
    wt[idx] = f2bf(v);
}

// ---------------------------------------------------------------------------
// K3: MFMA dense pass with mirror-pair reuse.
// Block = (b, pair p=(It<=Jt), io). i = It*64+io; J = Jt*64. M=64 (j-rows), K=96.
// A-row r = [x(b,i,J+r,0:48) | x(b,J+r,i,0:48)] (bf16, stride KP).
//   pass0 (direct): out(i, J+r, f) = xij.w12 + xji.w11   (A halves as-is)
//   pass1 (mirror, It!=Jt): out(J+r, i, f) = xji.w12 + xij.w11 (A halves swapped)
// Each out cell written exactly once: direct iff Tile(row)<=Tile(col).
// ---------------------------------------------------------------------------
__global__ __launch_bounds__(256) void k3_mfma(const float* __restrict__ x,
                                               const unsigned short* __restrict__ wt,
                                               const float* __restrict__ add_i,
                                               const float* __restrict__ add_j,
                                               const float* __restrict__ add_d,
                                               float* __restrict__ out) {
    __shared__ unsigned short Al[64 * KP];   // 13312 B
    __shared__ unsigned short Bl[96 * KP];   // 19968 B
    const int idx = blockIdx.x;              // 0..639
    const int b   = blockIdx.y;
    const int p   = idx >> 6;                // 0..9 pair id
    const int io  = idx & 63;
    int It, Jt;
    if (p < 4)      { It = 0; Jt = p; }
    else if (p < 7) { It = 1; Jt = p - 3; }
    else if (p < 9) { It = 2; Jt = p - 5; }
    else            { It = 3; Jt = 3; }
    const int i  = It * 64 + io;
    const int J  = Jt * 64;
    const int bi = b * Nx + i;
    const int t  = threadIdx.x;

    // stage B: 96*KP bf16 = 1248 uint4
    {
        const uint4* src = (const uint4*)wt;
        uint4* dst = (uint4*)Bl;
        #pragma unroll
        for (int it = 0; it < 5; ++it) {
            const int k = t + it * 256;
            if (k < (96 * KP * 2) / 16) dst[k] = src[k];
        }
    }
    // stage A: row r = t/4, quarter q = t&3
    {
        const int r = t >> 2, q = t & 3;
        const float* pij = x + ((size_t)bi * Nx + J + r) * Lx;
        const float* pji = x + ((size_t)(b * Nx + J + r) * Nx + i) * Lx;
        unsigned int* arow = (unsigned int*)Al + r * (KP / 2);
        #pragma unroll
        for (int e = 0; e < 3; ++e) {
            const float4 v = *(const float4*)(pij + q * 4 + e * 16);
            arow[q * 2 + e * 8 + 0] = pack2(v.x, v.y);
            arow[q * 2 + e * 8 + 1] = pack2(v.z, v.w);
        }
        #pragma unroll
        for (int e = 0; e < 3; ++e) {
            const float4 v = *(const float4*)(pji + q * 4 + e * 16);
            arow[24 + q * 2 + e * 8 + 0] = pack2(v.x, v.y);
            arow[24 + q * 2 + e * 8 + 1] = pack2(v.z, v.w);
        }
    }
    __syncthreads();

    const int wave = t >> 6, lane = t & 63;
    const int lm = lane & 15, quad = lane >> 4;
    const int m0 = wave * 16;

    const float* aiP = add_i + (size_t)bi * Fx;
    const float* ajP = add_j + (size_t)bi * Fx;
    const float* adP = add_d + (size_t)bi * Fx;
    float* outP = out + (size_t)bi * Nx * Fx;

    const int npass = (It == Jt) ? 1 : 2;
    for (int pass = 0; pass < npass; ++pass) {
        bf16x8 afr[3];
        #pragma unroll
        for (int ks = 0; ks < 3; ++ks) {
            int off = ks * 32 + quad * 8;
            if (pass) off = (off < 48) ? off + 48 : off - 48;
            afr[ks] = *(const bf16x8*)(Al + (m0 + lm) * KP + off);
        }
        #pragma unroll
        for (int nt = 0; nt < 6; ++nt) {
            f32x4 c = {0.f, 0.f, 0.f, 0.f};
            #pragma unroll
            for (int ks = 0; ks < 3; ++ks) {
                const bf16x8 bfr = *(const bf16x8*)(Bl + (nt * 16 + lm) * KP + ks * 32 + quad * 8);
                c = __builtin_amdgcn_mfma_f32_16x16x32_bf16(afr[ks], bfr, c, 0, 0, 0);
            }
            const int f = nt * 16 + lm;
            if (pass == 0) {
                const float ai = aiP[f];
                #pragma unroll
                for (int reg = 0; reg < 4; ++reg) {
                    const int j = J + m0 + quad * 4 + reg;
                    float v = c[reg] + ai + add_j[((size_t)(b * Nx) + j) * Fx + f];
                    if (j == i) v += adP[f];
                    outP[(size_t)j * Fx + f] = v;
                }
            } else {
                const float aj = ajP[f];
                #pragma unroll
                for (int reg = 0; reg < 4; ++reg) {
                    const int row = J + m0 + quad * 4 + reg;
                    float v = c[reg] + aj + add_i[((size_t)(b * Nx) + row) * Fx + f];
                    out[((size_t)(b * Nx + row) * Nx + i) * Fx + f] = v;
                }
            }
        }
    }
}

// ---------------------------------------------------------------------------
extern "C" void kernel_launch(void* const* d_in, const int* in_sizes, int n_in,
                              void* d_out, int out_size, void* d_ws, size_t ws_size,
                              hipStream_t stream) {
    const float* x = (const float*)d_in[0];
    const float* w = (const float*)d_in[1];
    float* out = (float*)d_out;

    float* ws      = (float*)d_ws;
    float* rowsum  = ws;                                  // B*N*L
    float* colsum  = rowsum + (size_t)Bx * Nx * Lx;
    float* diagv   = colsum + (size_t)Bx * Nx * Lx;
    float* trace   = diagv  + (size_t)Bx * Nx * Lx;       // B*L
    float* totsum  = trace  + (size_t)Bx * Lx;
    float* add_i   = totsum + (size_t)Bx * Lx;            // B*N*F
    float* add_j   = add_i  + (size_t)Bx * Nx * Fx;
    float* add_d   = add_j  + (size_t)Bx * Nx * Fx;
    unsigned short* wtbf = (unsigned short*)(add_d + (size_t)Bx * Nx * Fx);

    k_row<<<Bx * Nx, 192, 0, stream>>>(x, rowsum, diagv);
    hipMemsetAsync(colsum, 0, (size_t)Bx * Nx * Lx * sizeof(float), stream);
    k_col<<<Bx * 16 * 8, 256, 0, stream>>>(x, colsum);
    k1b_trace<<<Bx, 64, 0, stream>>>(rowsum, diagv, trace, totsum);
    k2_vectors<<<Bx * Nx, 128, 0, stream>>>(w, rowsum, colsum, diagv, trace, totsum,
                                            add_i, add_j, add_d);
    k_w<<<(Fx * KP + 255) / 256, 256, 0, stream>>>(w, wtbf);
    dim3 g3(640, Bx);
    k3_mfma<<<g3, 256, 0, stream>>>(x, wtbf, add_i, add_j, add_d, out);
}